// Round 7
// baseline (351.729 us; speedup 1.0000x reference)
//
#include <hip/hip_runtime.h>
#include <stdint.h>

// MultiHeadAttentionProj: B=4, N=2048, D=512, H=8, HD=64
// cvtw (W->bf16 concat, q->bf16, maskprep fused) -> GEMM QKV (global_load_lds,
// 128x128, 3/CU) -> flash attn SPLIT-K over keys (grid 1024 = 4 blocks/CU,
// 16 iters/block, BM=128 kept so Q-reuse/per-CU staging unchanged; f32
// partial O + rowsum out; no-max exp2 softmax is linear in key-partials)
// -> combine (sum halves, normalize, bf16) -> GEMM out (128x64, 512 blocks).
// Attn math/layouts identical to R5/R6 (verified): in-register P via cvt_pk +
// permlane32_swap + V key-permutation, conflict-free XOR-swizzled K/V LDS,
// mask C-init, MFMA rowsum. Bias prefetched one tile ahead (late-issued).

typedef __attribute__((ext_vector_type(8))) short short8;
typedef __attribute__((ext_vector_type(4))) short short4v;
typedef __attribute__((ext_vector_type(4))) float f32x4;

#define DEV static __device__ __forceinline__

constexpr int Bc = 4, Nc = 2048, Dc = 512, Hc = 8, HDc = 64;
constexpr int Mc = Bc * Nc;        // 8192 rows
constexpr int QKVNc = 3 * Dc;      // 1536
constexpr float L2E = 1.44269504f;
constexpr size_t OP_HALF = (size_t)32 * 16 * 128 * 64;   // floats per key-half
constexpr size_t RS_HALF = (size_t)32 * 16 * 128;        // rowsums per key-half

DEV short bf16cast(float f) {      // f32 -> bf16 bits (RNE via HW cvt)
  return (short)__builtin_bit_cast(unsigned short, (__bf16)f);
}
DEV unsigned cvt_pk_bf16(float a, float b) {  // a->low16, b->high16 (RNE)
  unsigned short lb = __builtin_bit_cast(unsigned short, (__bf16)a);
  unsigned short hb = __builtin_bit_cast(unsigned short, (__bf16)b);
  return (unsigned)lb | ((unsigned)hb << 16);
}
DEV unsigned pack_shorts(short a, short b) {
  return (unsigned)(unsigned short)a | ((unsigned)(unsigned short)b << 16);
}
DEV float fast_exp2(float x) {
#if __has_builtin(__builtin_amdgcn_exp2f)
  return __builtin_amdgcn_exp2f(x);
#else
  return exp2f(x);
#endif
}
// HW-verified (R3/R4): after op, a = [a.lo32, b.lo32], b = [a.hi32, b.hi32]
DEV void permswap32(unsigned& a, unsigned& b) {
  asm volatile("v_permlane32_swap_b32 %0, %1" : "+v"(a), "+v"(b));
}
// async global->LDS, 16B per lane; LDS dest = wave-uniform base + lane*16
DEV void gl_lds16(const short* g, short* l) {
  __builtin_amdgcn_global_load_lds(
      (const __attribute__((address_space(1))) void*)g,
      (__attribute__((address_space(3))) void*)l, 16, 0, 0);
}

// Blocks 0..1023: Wq,Wk,Wv -> Wqkv (concat), Wo -> Wob.
// Blocks 1024..5119: q (f32) -> qb (bf16).
// Block 5120: maskprep (detect dtype, convert to additive floats).
__global__ void cvtw_kernel(const float* __restrict__ Wq, const float* __restrict__ Wk,
                            const float* __restrict__ Wv, const float* __restrict__ Wo,
                            const float* __restrict__ q,
                            short* __restrict__ Wqkv, short* __restrict__ Wob,
                            short* __restrict__ qb,
                            const void* __restrict__ mask, float* __restrict__ mf) {
  int bid = blockIdx.x;
  if (bid >= 5120) {                                 // fused maskprep, 256 threads
    __shared__ int flag;
    if (threadIdx.x == 0) flag = 0;
    __syncthreads();
    const uchar4* m4 = (const uchar4*)mask;
    int acc = 0;
    for (int i = threadIdx.x; i < 2048; i += 256) {
      uchar4 v = m4[i];
      acc |= (int)v.y | (int)v.z | (int)v.w;
    }
    if (acc) atomicOr(&flag, 1);
    __syncthreads();
    int isbyte = flag;                               // int32 0/1 has bytes 1..3 zero
    for (int i = threadIdx.x; i < Bc * Nc; i += 256) {
      int v = isbyte ? (int)((const unsigned char*)mask)[i] : ((const int*)mask)[i];
      mf[i] = v ? -1e30f : 0.0f;
    }
    return;
  }
  const float* src; short* dst; int j;
  if (bid < 1024) {                                  // weights: 4 x 256 blocks
    int which = bid >> 8;
    j = (bid & 255) * 256 + threadIdx.x;             // float4 index < 65536
    src = which == 0 ? Wq : which == 1 ? Wk : which == 2 ? Wv : Wo;
    dst = (which == 3) ? Wob : Wqkv + which * (Dc * Dc);
  } else {                                           // q: 4096 blocks
    j = (bid - 1024) * 256 + threadIdx.x;            // float4 index < 1048576
    src = q; dst = qb;
  }
  float4 v = ((const float4*)src)[j];
  short4v o = { bf16cast(v.x), bf16cast(v.y), bf16cast(v.z), bf16cast(v.w) };
  ((short4v*)dst)[j] = o;
}

// C[M][N] = sum_k A[m][k]*Bm[n][k], A/B bf16. m97 structure: 128xBN tile,
// BK=64, global_load_lds (16B) staging with linear LDS + per-lane XOR-swizzled
// global source (chunk ^= row&7); swizzled conflict-free b128 frag reads.
template<int BN, bool OUT_F32, int MINW>
__global__ __launch_bounds__(256, MINW) void gemm_bt(const short* __restrict__ A,
                                                     const short* __restrict__ Bm,
                                                     void* __restrict__ Cv,
                                                     int M, int N, int K,
                                                     int qcols, float cscale) {
  constexpr int MT = (BN == 128) ? 4 : 2;
  constexpr int NT = 4;
  __shared__ __align__(16) short At[128 * 64];
  __shared__ __align__(16) short Bt[BN * 64];
  const int tid = threadIdx.x, lane = tid & 63, wv = tid >> 6;
  const int quad = lane >> 4, l16 = lane & 15;
  const int mbase = blockIdx.y * 128, nbase = blockIdx.x * BN;
  const int wr = (BN == 128) ? (wv >> 1) * 64 : wv * 32;
  const int wc = (BN == 128) ? (wv & 1) * 64 : 0;
  const float scale = (nbase < qcols) ? cscale : 1.0f;
  f32x4 acc[MT][NT] = {};

  for (int k0 = 0; k0 < K; k0 += 64) {
#pragma unroll
    for (int i = 0; i < 4; i++) {
      int ibase = (wv * 4 + i) * 64;                 // chunk index base
      int row = (ibase + lane) >> 3, c = lane & 7;
      gl_lds16(&A[(size_t)(mbase + row) * K + k0 + ((c ^ (row & 7)) << 3)],
               &At[ibase << 3]);
    }
#pragma unroll
    for (int i = 0; i < BN / 32; i++) {
      int ibase = (wv * (BN / 32) + i) * 64;
      int row = (ibase + lane) >> 3, c = lane & 7;
      gl_lds16(&Bm[(size_t)(nbase + row) * K + k0 + ((c ^ (row & 7)) << 3)],
               &Bt[ibase << 3]);
    }
    __syncthreads();                                 // drains vmcnt: tiles ready
#pragma unroll
    for (int s = 0; s < 2; s++) {
      short8 af[MT], bf[NT];
#pragma unroll
      for (int t = 0; t < MT; t++) {
        int r = wr + t * 16 + l16;
        af[t] = *(short8*)&At[r * 64 + (((quad + 4 * s) ^ (r & 7)) << 3)];
      }
#pragma unroll
      for (int t = 0; t < NT; t++) {
        int r = wc + t * 16 + l16;
        bf[t] = *(short8*)&Bt[r * 64 + (((quad + 4 * s) ^ (r & 7)) << 3)];
      }
#pragma unroll
      for (int mt = 0; mt < MT; mt++)
#pragma unroll
        for (int nt = 0; nt < NT; nt++)
          acc[mt][nt] = __builtin_amdgcn_mfma_f32_16x16x32_bf16(af[mt], bf[nt], acc[mt][nt], 0, 0, 0);
    }
    __syncthreads();                                 // reads done before next stage
  }
#pragma unroll
  for (int mt = 0; mt < MT; mt++)
#pragma unroll
    for (int nt = 0; nt < NT; nt++)
#pragma unroll
      for (int r = 0; r < 4; r++) {                  // C/D: row=quad*4+r, col=l16
        int row = mbase + wr + mt * 16 + quad * 4 + r;
        int col = nbase + wc + nt * 16 + l16;
        float v = acc[mt][nt][r] * scale;
        if (OUT_F32) ((float*)Cv)[(size_t)row * N + col] = v;
        else         ((short*)Cv)[(size_t)row * N + col] = bf16cast(v);
      }
}

// Flash attention, split-K over keys. blockIdx.x = (((b*8+h)*16+qt)<<1)|half;
// each block handles keys [half*1024, half*1024+1024) for 128 q-rows.
// 256 thr = 4 waves x 32 q-rows, 64-key tiles (16 iters), single-barrier dbuf
// swizzled K/V LDS. Writes f32 partial O + rowsum (no normalize) to workspace.
__global__ __launch_bounds__(256, 4) void attn_kernel(const short* __restrict__ QKV,
                                                      const float* __restrict__ bias,
                                                      const float* __restrict__ maskf,
                                                      float* __restrict__ Opart,
                                                      float* __restrict__ rsv) {
  __shared__ __align__(16) short Kt[2][64 * 64];     // [key][hd], dbuf, swizzled
  __shared__ __align__(16) short Vt[2][64 * 64];     // [hd][key_perm], dbuf, swizzled
  __shared__ __align__(16) float mlds[1024];         // this half's mask
  const int tid = threadIdx.x, lane = tid & 63, wv = tid >> 6;   // wv 0..3
  const int quad = lane >> 4, l16 = lane & 15;
  const int half = blockIdx.x & 1;
  const int rest = blockIdx.x >> 1;
  const int qt = rest & 15, h = (rest >> 4) & 7, b = rest >> 7;
  const int key0 = half * 1024;
  const int qrow0 = qt * 128;
  const int q0 = qrow0 + wv * 32 + l16;              // n=0 q-row; n=1 is q0+16
  const float* biasq0 = bias + ((size_t)b * Nc + q0) * Nc + key0;
  const float* biasq1 = biasq0 + (size_t)16 * Nc;

  ((float4*)mlds)[tid] = ((const float4*)(maskf + b * Nc + key0))[tid];  // 1024 f

  short8 qf[2][2];  // [n][s]: Q (pre-scaled 0.125*log2e), q=n*16+l16, k=quad*8+32s+j
  {
    const short* qp0 = QKV + (size_t)(b * Nc + q0) * QKVNc + h * HDc + quad * 8;
    qf[0][0] = *(const short8*)qp0;
    qf[0][1] = *(const short8*)(qp0 + 32);
    const short* qp1 = qp0 + (size_t)16 * QKVNc;
    qf[1][0] = *(const short8*)qp1;
    qf[1][1] = *(const short8*)(qp1 + 32);
  }

  // staging assignments (256 threads)
  const int krow = tid >> 2, kch0 = (tid & 3) * 2;   // K: row, 2 chunks/thread
  const int kw0 = krow * 64 + ((kch0 ^ (krow & 7)) << 3);
  const int kw1 = krow * 64 + (((kch0 + 1) ^ (krow & 7)) << 3);
  const int vp = tid & 31, vq = tid >> 5;            // V: key-pair, hd-oct 0..7
  const int vperm = (vp & 25) | ((vp & 4) >> 1) | ((vp & 2) << 1);  // key bits 3<->2
  const int vwbase = (((vperm >> 2)) << 3) + 2 * (vperm & 3);
  const short* Kbase = QKV + Dc + h * HDc;
  const short* Vbase = QKV + 2 * Dc + h * HDc;

  short8 kpre0, kpre1, v0pre, v1pre;
  {
    const short* kp = &Kbase[(size_t)(b * Nc + key0 + krow) * QKVNc + kch0 * 8];
    kpre0 = *(const short8*)kp;
    kpre1 = *(const short8*)(kp + 8);
    v0pre = *(const short8*)&Vbase[(size_t)(b * Nc + key0 + 2 * vp) * QKVNc + vq * 8];
    v1pre = *(const short8*)&Vbase[(size_t)(b * Nc + key0 + 2 * vp + 1) * QKVNc + vq * 8];
  }
  float4 bpre[2][4];                                 // bias prefetch, 1 tile ahead
#pragma unroll
  for (int t = 0; t < 4; t++) {
    bpre[0][t] = *(const float4*)&biasq0[t * 16 + quad * 4];
    bpre[1][t] = *(const float4*)&biasq1[t * 16 + quad * 4];
  }

  const short ONEB = (short)0x3F80;                  // bf16 1.0
  const short8 ones = { ONEB, ONEB, ONEB, ONEB, ONEB, ONEB, ONEB, ONEB };

  f32x4 oacc[2][4] = {};                             // [m][t]: row q=m*16+quad*4+r, col hd=16t+l16
  f32x4 sumacc[2] = {};                              // rowsum per m-tile

  for (int kt = 0; kt < 16; kt++) {
    const int cur = kt & 1;
    const int kb = kt * 64;                          // local within this half
    const int kbn = ((kt + 1) & 15) * 64;            // next (wraps, in-bounds)

    // W: regs -> LDS buf[cur] (swizzled)
    *(short8*)&Kt[cur][kw0] = kpre0;
    *(short8*)&Kt[cur][kw1] = kpre1;
#pragma unroll
    for (int j = 0; j < 8; j++) {                    // V -> LDS transposed (b32)
      int hd = vq * 8 + j;
      *(unsigned*)&Vt[cur][hd * 64 + (vwbase ^ ((hd & 7) << 3))] =
          pack_shorts(v0pre[j], v1pre[j]);
    }
    __syncthreads();                                 // ONE barrier per tile

    // K/V prefetch for next tile — issued early, consumed next iteration
    {
      const short* kp = &Kbase[(size_t)(b * Nc + key0 + kbn + krow) * QKVNc + kch0 * 8];
      kpre0 = *(const short8*)kp;
      kpre1 = *(const short8*)(kp + 8);
      v0pre = *(const short8*)&Vbase[(size_t)(b * Nc + key0 + kbn + 2 * vp) * QKVNc + vq * 8];
      v1pre = *(const short8*)&Vbase[(size_t)(b * Nc + key0 + kbn + 2 * vp + 1) * QKVNc + vq * 8];
    }

    // C-init = mask (broadcast LDS reads; same for both n-tiles)
    f32x4 sacc[2][4];
#pragma unroll
    for (int t = 0; t < 4; t++) {
      float4 mv = *(const float4*)&mlds[kb + t * 16 + quad * 4];
      sacc[0][t][0] = mv.x; sacc[0][t][1] = mv.y; sacc[0][t][2] = mv.z; sacc[0][t][3] = mv.w;
      sacc[1][t] = sacc[0][t];
    }

    // QK^T: S^T[key=16t+4quad+r][q=n*16+l16]; kf shared across n
#pragma unroll
    for (int s = 0; s < 2; s++)
#pragma unroll
      for (int t = 0; t < 4; t++) {
        short8 kf = *(short8*)&Kt[cur][(t * 16 + l16) * 64 + (((quad + 4 * s) ^ (l16 & 7)) << 3)];
        sacc[0][t] = __builtin_amdgcn_mfma_f32_16x16x32_bf16(kf, qf[0][s], sacc[0][t], 0, 0, 0);
        sacc[1][t] = __builtin_amdgcn_mfma_f32_16x16x32_bf16(kf, qf[1][s], sacc[1][t], 0, 0, 0);
      }

    // softmax: p = exp2(bias*log2e + s_with_mask); consumes bpre (cur tile)
    short8 pf[2][2];
#pragma unroll
    for (int n = 0; n < 2; n++) {
      unsigned pw[4][2];
#pragma unroll
      for (int t = 0; t < 4; t++) {
        float p0 = fast_exp2(__builtin_fmaf(bpre[n][t].x, L2E, sacc[n][t][0]));
        float p1 = fast_exp2(__builtin_fmaf(bpre[n][t].y, L2E, sacc[n][t][1]));
        float p2 = fast_exp2(__builtin_fmaf(bpre[n][t].z, L2E, sacc[n][t][2]));
        float p3 = fast_exp2(__builtin_fmaf(bpre[n][t].w, L2E, sacc[n][t][3]));
        pw[t][0] = cvt_pk_bf16(p0, p1);
        pw[t][1] = cvt_pk_bf16(p2, p3);
      }
      permswap32(pw[0][0], pw[1][0]); permswap32(pw[0][1], pw[1][1]);
      permswap32(pw[2][0], pw[3][0]); permswap32(pw[2][1], pw[3][1]);
      union { unsigned u[4]; short8 s; }
          a0{{pw[0][0], pw[0][1], pw[1][0], pw[1][1]}},
          a1{{pw[2][0], pw[2][1], pw[3][0], pw[3][1]}};
      pf[n][0] = a0.s; pf[n][1] = a1.s;
    }

    // bias prefetch for next tile (late issue: aged through PV + staging + QK^T)
#pragma unroll
    for (int t = 0; t < 4; t++) {
      bpre[0][t] = *(const float4*)&biasq0[kbn + t * 16 + quad * 4];
      bpre[1][t] = *(const float4*)&biasq1[kbn + t * 16 + quad * 4];
    }

    // PV: O += P·V (permuted contraction, matches Vt layout); rowsum += P·1
#pragma unroll
    for (int s = 0; s < 2; s++) {
      sumacc[0] = __builtin_amdgcn_mfma_f32_16x16x32_bf16(pf[0][s], ones, sumacc[0], 0, 0, 0);
      sumacc[1] = __builtin_amdgcn_mfma_f32_16x16x32_bf16(pf[1][s], ones, sumacc[1], 0, 0, 0);
#pragma unroll
      for (int t = 0; t < 4; t++) {
        short8 vf = *(short8*)&Vt[cur][(t * 16 + l16) * 64 + (((quad + 4 * s) ^ (l16 & 7)) << 3)];
        oacc[0][t] = __builtin_amdgcn_mfma_f32_16x16x32_bf16(pf[0][s], vf, oacc[0][t], 0, 0, 0);
        oacc[1][t] = __builtin_amdgcn_mfma_f32_16x16x32_bf16(pf[1][s], vf, oacc[1][t], 0, 0, 0);
      }
    }
  }

  // epilogue: store f32 partial O + rowsum (no normalize)
  const size_t blk = (size_t)(b * 8 + h) * 16 + qt;
  float* Op = Opart + (size_t)half * OP_HALF + blk * (128 * 64);
  float* Rs = rsv + (size_t)half * RS_HALF + blk * 128;
#pragma unroll
  for (int m = 0; m < 2; m++)
#pragma unroll
    for (int r = 0; r < 4; r++) {
      int q = wv * 32 + m * 16 + quad * 4 + r;
#pragma unroll
      for (int t = 0; t < 4; t++)
        Op[(size_t)q * 64 + t * 16 + l16] = oacc[m][t][r];
      if (l16 == 0) Rs[q] = sumacc[m][r];
    }
}

// Sum the two key-half partials, normalize by combined rowsum, cast to bf16.
// idx -> (row, h, 8-hd chunk); writes are fully coalesced per 64 threads.
__global__ __launch_bounds__(256) void combine_kernel(const float* __restrict__ Opart,
                                                      const float* __restrict__ rsv,
                                                      short* __restrict__ Aout) {
  int idx = blockIdx.x * 256 + threadIdx.x;          // < 524288
  int oct = idx & 7, hh = (idx >> 3) & 7, row = idx >> 6;
  int b = row >> 11, qg = row & 2047;
  int qt = qg >> 7, qq = qg & 127;
  size_t blk = (size_t)(b * 8 + hh) * 16 + qt;
  size_t base = (blk * 128 + qq) * 64 + (size_t)oct * 8;
  float4 a0 = *(const float4*)&Opart[base];
  float4 a1 = *(const float4*)&Opart[base + 4];
  float4 c0 = *(const float4*)&Opart[OP_HALF + base];
  float4 c1 = *(const float4*)&Opart[OP_HALF + base + 4];
  float inv = 1.0f / (rsv[blk * 128 + qq] + rsv[RS_HALF + blk * 128 + qq]);
  short8 o = { bf16cast((a0.x + c0.x) * inv), bf16cast((a0.y + c0.y) * inv),
               bf16cast((a0.z + c0.z) * inv), bf16cast((a0.w + c0.w) * inv),
               bf16cast((a1.x + c1.x) * inv), bf16cast((a1.y + c1.y) * inv),
               bf16cast((a1.z + c1.z) * inv), bf16cast((a1.w + c1.w) * inv) };
  *(short8*)&Aout[(size_t)row * Dc + hh * HDc + oct * 8] = o;
}

extern "C" void kernel_launch(void* const* d_in, const int* in_sizes, int n_in,
                              void* d_out, int out_size, void* d_ws, size_t ws_size,
                              hipStream_t stream) {
  const float* q    = (const float*)d_in[0];
  const void*  mask = d_in[1];
  const float* bias = (const float*)d_in[2];
  const float* Wq   = (const float*)d_in[3];
  const float* Wk   = (const float*)d_in[4];
  const float* Wv   = (const float*)d_in[5];
  const float* Wo   = (const float*)d_in[6];
  float* out = (float*)d_out;

  char* ws = (char*)d_ws;
  short* Wqkv = (short*)ws;  ws += (size_t)QKVNc * Dc * 2;
  short* Wob  = (short*)ws;  ws += (size_t)Dc * Dc * 2;
  float* mf   = (float*)ws;  ws += (size_t)Bc * Nc * 4;
  short* QKV  = (short*)ws;  ws += (size_t)Mc * QKVNc * 2;
  short* aout = (short*)ws;  ws += (size_t)Mc * Dc * 2;
  // union region: qb (live cvtw->GEMM1) overlapped with Opart/rsv (attn->combine)
  char* ubase = ws;
  short* qb    = (short*)ubase;                              // 8.4 MB
  float* Opart = (float*)ubase;                              // 33.6 MB
  float* rsv   = (float*)(ubase + OP_HALF * 2 * sizeof(float));  // 0.5 MB

  cvtw_kernel<<<dim3(5121), dim3(256), 0, stream>>>(Wq, Wk, Wv, Wo, q, Wqkv, Wob, qb, mask, mf);

  // Q pre-scaled (epilogue) by 0.125*log2e so attn can use exp2 directly.
  gemm_bt<128, false, 3><<<dim3(QKVNc / 128, Mc / 128), dim3(256), 0, stream>>>(
      qb, Wqkv, (void*)QKV, Mc, QKVNc, Dc, Dc, 0.125f * L2E);
  attn_kernel<<<dim3(Bc * Hc * 16 * 2), dim3(256), 0, stream>>>(QKV, bias, mf, Opart, rsv);
  combine_kernel<<<dim3(2048), dim3(256), 0, stream>>>(Opart, rsv, aout);
  gemm_bt<64, true, 4><<<dim3(Dc / 64, Mc / 128), dim3(256), 0, stream>>>(
      aout, Wob, (void*)out, Mc, Dc, Dc, 0, 1.0f);
}

// Round 8
// 256.445 us; speedup vs baseline: 1.3716x; 1.3716x over previous
//
#include <hip/hip_runtime.h>
#include <stdint.h>

// MultiHeadAttentionProj: B=4, N=2048, D=512, H=8, HD=64
// THREE launches:
//  gemm_bt<A_F32=1,BN=128> : QKV = q @ [Wq|Wk|Wv]^T  (f32 A and B converted
//    during LDS staging — cvtw/maskprep kernels deleted; Q cols scaled
//    0.125*log2e in epilogue)
//  attn_kernel : R5/R6-verified core (4 waves x 32 q, in-register P via
//    cvt_pk+permlane32_swap+V key-perm, XOR-swizzled conflict-free LDS,
//    exp2 softmax, MFMA rowsum) + K staged via global_load_lds (R6-verified
//    addressing) + s_setprio around MFMA clusters + inline mask convert.
//  gemm_bt<A_F32=0,BN=64>  : out = aout @ Wo^T (Wo f32 converted in staging)

typedef __attribute__((ext_vector_type(8))) short short8;
typedef __attribute__((ext_vector_type(4))) short short4v;
typedef __attribute__((ext_vector_type(4))) float f32x4;

#define DEV static __device__ __forceinline__

constexpr int Bc = 4, Nc = 2048, Dc = 512, Hc = 8, HDc = 64;
constexpr int Mc = Bc * Nc;        // 8192 rows
constexpr int QKVNc = 3 * Dc;      // 1536
constexpr float L2E = 1.44269504f;

DEV short bf16cast(float f) {      // f32 -> bf16 bits (RNE via HW cvt)
  return (short)__builtin_bit_cast(unsigned short, (__bf16)f);
}
DEV unsigned cvt_pk_bf16(float a, float b) {  // a->low16, b->high16 (RNE)
  unsigned short lb = __builtin_bit_cast(unsigned short, (__bf16)a);
  unsigned short hb = __builtin_bit_cast(unsigned short, (__bf16)b);
  return (unsigned)lb | ((unsigned)hb << 16);
}
DEV unsigned pack_shorts(short a, short b) {
  return (unsigned)(unsigned short)a | ((unsigned)(unsigned short)b << 16);
}
DEV short8 cvt8(float4 a, float4 b) {   // 8 f32 -> short8 bf16
  union { short8 s; uint4 u; } r;
  r.u.x = cvt_pk_bf16(a.x, a.y); r.u.y = cvt_pk_bf16(a.z, a.w);
  r.u.z = cvt_pk_bf16(b.x, b.y); r.u.w = cvt_pk_bf16(b.z, b.w);
  return r.s;
}
DEV float fast_exp2(float x) {
#if __has_builtin(__builtin_amdgcn_exp2f)
  return __builtin_amdgcn_exp2f(x);
#else
  return exp2f(x);
#endif
}
// HW-verified (R3/R4): after op, a = [a.lo32, b.lo32], b = [a.hi32, b.hi32]
DEV void permswap32(unsigned& a, unsigned& b) {
  asm volatile("v_permlane32_swap_b32 %0, %1" : "+v"(a), "+v"(b));
}
// async global->LDS, 16B per lane; LDS dest = wave-uniform base + lane*16
DEV void gl_lds16(const short* g, short* l) {
  __builtin_amdgcn_global_load_lds(
      (const __attribute__((address_space(1))) void*)g,
      (__attribute__((address_space(3))) void*)l, 16, 0, 0);
}

// C[M][N] = sum_k A[m][k]*W[n][k]. 128xBN tile, BK=64, rows padded to 72
// shorts; reg-prefetch pipeline (R5-verified structure). A: f32 or bf16
// (A_F32). B: ALWAYS f32 (Wq/Wk/Wv/Wo read directly; converted in staging).
// B pointer picked per block from {B0,B1,B2} by nbase>>9 (512-col segments).
template<bool A_F32, int BN, bool OUT_F32>
__global__ __launch_bounds__(256, 2) void gemm_bt(const void* __restrict__ Av,
                                                  const float* __restrict__ B0,
                                                  const float* __restrict__ B1,
                                                  const float* __restrict__ B2,
                                                  void* __restrict__ Cv,
                                                  int M, int N,
                                                  int qcols, float cscale) {
  constexpr int K = 512;                 // = W row stride
  constexpr int BG = BN / 32;            // B staging chunk-groups (4 or 2)
  constexpr int MT = (BN == 128) ? 4 : 2;
  constexpr int NT = 4;
  __shared__ __align__(16) short At[128 * 72];
  __shared__ __align__(16) short Bt[BN * 72];
  const int tid = threadIdx.x, lane = tid & 63, wv = tid >> 6;
  const int quad = lane >> 4, l16 = lane & 15;
  const int mbase = blockIdx.y * 128, nbase = blockIdx.x * BN;
  const int wr = (BN == 128) ? (wv >> 1) * 64 : wv * 32;
  const int wc = (BN == 128) ? (wv & 1) * 64 : 0;
  const float* Bsel = nbase < 512 ? B0 : (nbase < 1024 ? B1 : B2);
  const int col0 = nbase & 511;
  const float scale = (nbase < qcols) ? cscale : 1.0f;
  f32x4 acc[MT][NT] = {};
  float4 apf[4][2]; short8 aph[4];
  float4 bpf[BG][2];
#pragma unroll
  for (int i = 0; i < 4; i++) {                 // preload A, k0=0
    int flat = i * 256 + tid, row = flat >> 3, ch8 = (flat & 7) * 8;
    if (A_F32) {
      const float* Af = (const float*)Av;
      apf[i][0] = *(const float4*)&Af[(size_t)(mbase + row) * K + ch8];
      apf[i][1] = *(const float4*)&Af[(size_t)(mbase + row) * K + ch8 + 4];
    } else {
      aph[i] = *(const short8*)&((const short*)Av)[(size_t)(mbase + row) * K + ch8];
    }
  }
#pragma unroll
  for (int i = 0; i < BG; i++) {                // preload B (f32), k0=0
    int flat = i * 256 + tid, row = flat >> 3, ch8 = (flat & 7) * 8;
    bpf[i][0] = *(const float4*)&Bsel[(size_t)(col0 + row) * K + ch8];
    bpf[i][1] = *(const float4*)&Bsel[(size_t)(col0 + row) * K + ch8 + 4];
  }
  for (int k0 = 0; k0 < K; k0 += 64) {
    __syncthreads();
#pragma unroll
    for (int i = 0; i < 4; i++) {
      int flat = i * 256 + tid, row = flat >> 3, ch8 = (flat & 7) * 8;
      *(short8*)&At[row * 72 + ch8] = A_F32 ? cvt8(apf[i][0], apf[i][1]) : aph[i];
    }
#pragma unroll
    for (int i = 0; i < BG; i++) {
      int flat = i * 256 + tid, row = flat >> 3, ch8 = (flat & 7) * 8;
      *(short8*)&Bt[row * 72 + ch8] = cvt8(bpf[i][0], bpf[i][1]);
    }
    if (k0 + 64 < K) {
#pragma unroll
      for (int i = 0; i < 4; i++) {             // prefetch next A
        int flat = i * 256 + tid, row = flat >> 3, ch8 = (flat & 7) * 8;
        if (A_F32) {
          const float* Af = (const float*)Av;
          apf[i][0] = *(const float4*)&Af[(size_t)(mbase + row) * K + k0 + 64 + ch8];
          apf[i][1] = *(const float4*)&Af[(size_t)(mbase + row) * K + k0 + 64 + ch8 + 4];
        } else {
          aph[i] = *(const short8*)&((const short*)Av)[(size_t)(mbase + row) * K + k0 + 64 + ch8];
        }
      }
#pragma unroll
      for (int i = 0; i < BG; i++) {            // prefetch next B
        int flat = i * 256 + tid, row = flat >> 3, ch8 = (flat & 7) * 8;
        bpf[i][0] = *(const float4*)&Bsel[(size_t)(col0 + row) * K + k0 + 64 + ch8];
        bpf[i][1] = *(const float4*)&Bsel[(size_t)(col0 + row) * K + k0 + 64 + ch8 + 4];
      }
    }
    __syncthreads();
#pragma unroll
    for (int s = 0; s < 2; s++) {
      short8 af[MT], bf[NT];
#pragma unroll
      for (int t = 0; t < MT; t++)
        af[t] = *(short8*)&At[(wr + t * 16 + l16) * 72 + quad * 8 + s * 32];
#pragma unroll
      for (int t = 0; t < NT; t++)
        bf[t] = *(short8*)&Bt[(wc + t * 16 + l16) * 72 + quad * 8 + s * 32];
#pragma unroll
      for (int mt = 0; mt < MT; mt++)
#pragma unroll
        for (int nt = 0; nt < NT; nt++)
          acc[mt][nt] = __builtin_amdgcn_mfma_f32_16x16x32_bf16(af[mt], bf[nt], acc[mt][nt], 0, 0, 0);
    }
  }
#pragma unroll
  for (int mt = 0; mt < MT; mt++)
#pragma unroll
    for (int nt = 0; nt < NT; nt++)
#pragma unroll
      for (int r = 0; r < 4; r++) {             // C/D: row=quad*4+r, col=l16
        int row = mbase + wr + mt * 16 + quad * 4 + r;
        int col = nbase + wc + nt * 16 + l16;
        float v = acc[mt][nt][r] * scale;
        if (OUT_F32) ((float*)Cv)[(size_t)row * N + col] = v;
        else         ((short*)Cv)[(size_t)row * N + col] = bf16cast(v);
      }
}

// Flash attention — R5/R6-verified core. S^T form, BM=128, 256 thr = 4 waves
// x 32 q-rows, 64-key tiles, single-barrier dbuf LDS (pitch 64, chunk^(row&7)
// swizzle). NEW this round: K staged via global_load_lds (linear dest,
// pre-swizzled source — R6-gemm-verified pattern), s_setprio(1) around MFMA
// clusters, raw mask converted inline (maskprep kernel + mf buffer deleted).
__global__ __launch_bounds__(256, 2) void attn_kernel(const short* __restrict__ QKV,
                                                      const float* __restrict__ bias,
                                                      const void* __restrict__ mask,
                                                      short* __restrict__ Aout) {
  __shared__ __align__(16) short Kt[2][64 * 64];     // [key][hd], dbuf, swizzled
  __shared__ __align__(16) short Vt[2][64 * 64];     // [hd][key_perm], dbuf, swizzled
  __shared__ __align__(16) float mlds[Nc];
  __shared__ int mflag;
  const int tid = threadIdx.x, lane = tid & 63, wv = tid >> 6;   // wv 0..3
  const int quad = lane >> 4, l16 = lane & 15;
  const int qt = blockIdx.x & 15, h = (blockIdx.x >> 4) & 7, b = (int)(blockIdx.x >> 7);
  const int qrow0 = qt * 128;
  const int q0 = qrow0 + wv * 32 + l16;              // n=0 q-row; n=1 is q0+16
  const float* biasq0 = bias + ((size_t)b * Nc + q0) * Nc;
  const float* biasq1 = biasq0 + (size_t)16 * Nc;
  const short* Kbase = QKV + Dc + h * HDc;
  const short* Vbase = QKV + 2 * Dc + h * HDc;

  // ---- issue K gl_lds for tile 0 immediately (ages through prologue) ----
#pragma unroll
  for (int j = 0; j < 2; j++) {
    int seg = wv * 2 + j, c = seg * 64 + lane;
    int row = c >> 3, ch = c & 7;
    gl_lds16(&Kbase[(size_t)(b * Nc + row) * QKVNc + ((ch ^ (row & 7)) << 3)],
             &Kt[0][seg * 512]);
  }

  short8 qf[2][2];  // [n][s]: Q (pre-scaled 0.125*log2e), q=n*16+l16, k=quad*8+32s+j
  {
    const short* qp0 = QKV + (size_t)(b * Nc + q0) * QKVNc + h * HDc + quad * 8;
    qf[0][0] = *(const short8*)qp0;
    qf[0][1] = *(const short8*)(qp0 + 32);
    const short* qp1 = qp0 + (size_t)16 * QKVNc;
    qf[1][0] = *(const short8*)qp1;
    qf[1][1] = *(const short8*)(qp1 + 32);
  }

  // V staging assignment (reg-staged: needs transpose+pack, gl_lds can't)
  const int vp = tid & 31, vq = tid >> 5;            // V: key-pair, hd-oct 0..7
  const int vperm = (vp & 25) | ((vp & 4) >> 1) | ((vp & 2) << 1);  // key bits 3<->2
  const int vwbase = (((vperm >> 2)) << 3) + 2 * (vperm & 3);

  short8 v0pre, v1pre;
  v0pre = *(const short8*)&Vbase[(size_t)(b * Nc + 2 * vp) * QKVNc + vq * 8];
  v1pre = *(const short8*)&Vbase[(size_t)(b * Nc + 2 * vp + 1) * QKVNc + vq * 8];
  float4 bpre[2][4];                                 // bias prefetch, 1 tile ahead
#pragma unroll
  for (int t = 0; t < 4; t++) {
    bpre[0][t] = *(const float4*)&biasq0[t * 16 + quad * 4];
    bpre[1][t] = *(const float4*)&biasq1[t * 16 + quad * 4];
  }

  // ---- inline mask convert: detect dtype on this b's slice, fill mlds ----
  // Window at BYTE offset b*2048 (2 KB) is in-bounds for both layouts; int32
  // data has bytes 1..3 of every word zero; byte data shows 1s there.
  if (tid == 0) mflag = 0;
  __syncthreads();
  {
    const uchar4* mw = (const uchar4*)((const char*)mask + (size_t)b * 2048);
    int acc = 0;
#pragma unroll
    for (int i = tid; i < 512; i += 256) {
      uchar4 v = mw[i];
      acc |= (int)v.y | (int)v.z | (int)v.w;
    }
    if (acc) atomicOr(&mflag, 1);
  }
  __syncthreads();
  {
    int isbyte = mflag;
    const unsigned char* mb = (const unsigned char*)mask + (size_t)b * 2048;
    const int* mi = (const int*)mask + (size_t)b * 2048;
    for (int i = tid; i < Nc; i += 256) {
      int v = isbyte ? (int)mb[i] : mi[i];
      mlds[i] = v ? -1e30f : 0.0f;
    }
  }

  const short ONEB = (short)0x3F80;                  // bf16 1.0
  const short8 ones = { ONEB, ONEB, ONEB, ONEB, ONEB, ONEB, ONEB, ONEB };

  f32x4 oacc[2][4] = {};                             // [m][t]: row q=m*16+quad*4+r, col hd=16t+l16
  f32x4 sumacc[2] = {};                              // rowsum per m-tile

  for (int kt = 0; kt < 32; kt++) {
    const int cur = kt & 1, nxt = cur ^ 1;
    const int kb = kt * 64;
    const int kbn = ((kt + 1) & 31) * 64;            // next tile (wraps, in-bounds)

    // W: V regs -> Vt[cur] (swizzled); Kt[cur] filled by gl_lds from prev iter
#pragma unroll
    for (int j = 0; j < 8; j++) {
      int hd = vq * 8 + j;
      *(unsigned*)&Vt[cur][hd * 64 + (vwbase ^ ((hd & 7) << 3))] =
          pack_shorts(v0pre[j], v1pre[j]);
    }
    __syncthreads();                                 // ONE barrier: drains gl_lds too

    // issue next tile: K via gl_lds -> Kt[nxt]; V via regs; (bias in softmax)
#pragma unroll
    for (int j = 0; j < 2; j++) {
      int seg = wv * 2 + j, c = seg * 64 + lane;
      int row = c >> 3, ch = c & 7;
      gl_lds16(&Kbase[(size_t)(b * Nc + kbn + row) * QKVNc + ((ch ^ (row & 7)) << 3)],
               &Kt[nxt][seg * 512]);
    }
    v0pre = *(const short8*)&Vbase[(size_t)(b * Nc + kbn + 2 * vp) * QKVNc + vq * 8];
    v1pre = *(const short8*)&Vbase[(size_t)(b * Nc + kbn + 2 * vp + 1) * QKVNc + vq * 8];

    // C-init = mask (broadcast LDS reads; same for both n-tiles)
    f32x4 sacc[2][4];
#pragma unroll
    for (int t = 0; t < 4; t++) {
      float4 mv = *(const float4*)&mlds[kb + t * 16 + quad * 4];
      sacc[0][t][0] = mv.x; sacc[0][t][1] = mv.y; sacc[0][t][2] = mv.z; sacc[0][t][3] = mv.w;
      sacc[1][t] = sacc[0][t];
    }

    // QK^T: S^T[key=16t+4quad+r][q=n*16+l16]; kf shared across n
    __builtin_amdgcn_s_setprio(1);
#pragma unroll
    for (int s = 0; s < 2; s++)
#pragma unroll
      for (int t = 0; t < 4; t++) {
        short8 kf = *(short8*)&Kt[cur][(t * 16 + l16) * 64 + (((quad + 4 * s) ^ (l16 & 7)) << 3)];
        sacc[0][t] = __builtin_amdgcn_mfma_f32_16x16x32_bf16(kf, qf[0][s], sacc[0][t], 0, 0, 0);
        sacc[1][t] = __builtin_amdgcn_mfma_f32_16x16x32_bf16(kf, qf[1][s], sacc[1][t], 0, 0, 0);
      }
    __builtin_amdgcn_s_setprio(0);

    // softmax: p = exp2(bias*log2e + s_with_mask); consumes bpre (cur tile)
    short8 pf[2][2];
#pragma unroll
    for (int n = 0; n < 2; n++) {
      unsigned pw[4][2];
#pragma unroll
      for (int t = 0; t < 4; t++) {
        float p0 = fast_exp2(__builtin_fmaf(bpre[n][t].x, L2E, sacc[n][t][0]));
        float p1 = fast_exp2(__builtin_fmaf(bpre[n][t].y, L2E, sacc[n][t][1]));
        float p2 = fast_exp2(__builtin_fmaf(bpre[n][t].z, L2E, sacc[n][t][2]));
        float p3 = fast_exp2(__builtin_fmaf(bpre[n][t].w, L2E, sacc[n][t][3]));
        pw[t][0] = cvt_pk_bf16(p0, p1);
        pw[t][1] = cvt_pk_bf16(p2, p3);
      }
      permswap32(pw[0][0], pw[1][0]); permswap32(pw[0][1], pw[1][1]);
      permswap32(pw[2][0], pw[3][0]); permswap32(pw[2][1], pw[3][1]);
      union { unsigned u[4]; short8 s; }
          a0{{pw[0][0], pw[0][1], pw[1][0], pw[1][1]}},
          a1{{pw[2][0], pw[2][1], pw[3][0], pw[3][1]}};
      pf[n][0] = a0.s; pf[n][1] = a1.s;
    }

    // bias prefetch for next tile (late issue; aged through PV + next QK^T)
#pragma unroll
    for (int t = 0; t < 4; t++) {
      bpre[0][t] = *(const float4*)&biasq0[kbn + t * 16 + quad * 4];
      bpre[1][t] = *(const float4*)&biasq1[kbn + t * 16 + quad * 4];
    }

    // PV: O += P·V (permuted contraction, matches Vt layout); rowsum += P·1
    __builtin_amdgcn_s_setprio(1);
#pragma unroll
    for (int s = 0; s < 2; s++) {
      sumacc[0] = __builtin_amdgcn_mfma_f32_16x16x32_bf16(pf[0][s], ones, sumacc[0], 0, 0, 0);
      sumacc[1] = __builtin_amdgcn_mfma_f32_16x16x32_bf16(pf[1][s], ones, sumacc[1], 0, 0, 0);
#pragma unroll
      for (int t = 0; t < 4; t++) {
        short8 vf = *(short8*)&Vt[cur][(t * 16 + l16) * 64 + (((quad + 4 * s) ^ (l16 & 7)) << 3)];
        oacc[0][t] = __builtin_amdgcn_mfma_f32_16x16x32_bf16(pf[0][s], vf, oacc[0][t], 0, 0, 0);
        oacc[1][t] = __builtin_amdgcn_mfma_f32_16x16x32_bf16(pf[1][s], vf, oacc[1][t], 0, 0, 0);
      }
    }
    __builtin_amdgcn_s_setprio(0);
  }

#pragma unroll
  for (int m = 0; m < 2; m++)
#pragma unroll
    for (int r = 0; r < 4; r++) {                    // O row q=m*16+quad*4+r, col hd=16t+l16
      float inv = 1.0f / sumacc[m][r];
      int row = b * Nc + qrow0 + wv * 32 + m * 16 + quad * 4 + r;
#pragma unroll
      for (int t = 0; t < 4; t++)
        Aout[(size_t)row * Dc + h * HDc + t * 16 + l16] = bf16cast(oacc[m][t][r] * inv);
    }
}

extern "C" void kernel_launch(void* const* d_in, const int* in_sizes, int n_in,
                              void* d_out, int out_size, void* d_ws, size_t ws_size,
                              hipStream_t stream) {
  const float* q    = (const float*)d_in[0];
  const void*  mask = d_in[1];
  const float* bias = (const float*)d_in[2];
  const float* Wq   = (const float*)d_in[3];
  const float* Wk   = (const float*)d_in[4];
  const float* Wv   = (const float*)d_in[5];
  const float* Wo   = (const float*)d_in[6];
  float* out = (float*)d_out;

  char* ws = (char*)d_ws;
  short* QKV  = (short*)ws;  ws += (size_t)Mc * QKVNc * 2;
  short* aout = (short*)ws;  ws += (size_t)Mc * Dc * 2;

  // QKV = q @ [Wq|Wk|Wv]^T, all conversion in-staging; Q cols scaled 0.125*L2E.
  gemm_bt<true, 128, false><<<dim3(QKVNc / 128, Mc / 128), dim3(256), 0, stream>>>(
      (const void*)q, Wq, Wk, Wv, (void*)QKV, Mc, QKVNc, Dc, 0.125f * L2E);
  attn_kernel<<<dim3(Bc * Hc * 16), dim3(256), 0, stream>>>(QKV, bias, mask, aout);
  gemm_bt<false, 64, true><<<dim3(Dc / 64, Mc / 128), dim3(256), 0, stream>>>(
      (const void*)aout, Wo, Wo, Wo, (void*)out, Mc, Dc, 0, 1.0f);
}

// Round 9
// 248.181 us; speedup vs baseline: 1.4172x; 1.0333x over previous
//
#include <hip/hip_runtime.h>
#include <stdint.h>

// MultiHeadAttentionProj: B=4, N=2048, D=512, H=8, HD=64
// THREE launches:
//  gemm_bt<A_F32=1,BN=128> : QKV = q @ [Wq|Wk|Wv]^T (conversion in staging;
//    Q cols scaled 0.125*log2e in epilogue)     [unchanged from R8 — control]
//  attn_kernel : R8-verified core (4 waves x 32 q, in-register P via
//    cvt_pk+permlane32_swap+V key-perm, XOR-swizzled conflict-free LDS,
//    exp2 softmax, MFMA rowsum, gl_lds K, setprio, inline mask convert)
//    NEW: TWO K-tiles per barrier period (4-buffer LDS rotation) — halves
//    barrier count and gives the scheduler two independent QK^T/SM/PV chains
//    per body so MFMA and VALU bursts overlap across tiles.
//  gemm_bt<A_F32=0,BN=64>  : out = aout @ Wo^T  [unchanged from R8 — control]

typedef __attribute__((ext_vector_type(8))) short short8;
typedef __attribute__((ext_vector_type(4))) short short4v;
typedef __attribute__((ext_vector_type(4))) float f32x4;

#define DEV static __device__ __forceinline__

constexpr int Bc = 4, Nc = 2048, Dc = 512, Hc = 8, HDc = 64;
constexpr int Mc = Bc * Nc;        // 8192 rows
constexpr int QKVNc = 3 * Dc;      // 1536
constexpr float L2E = 1.44269504f;

DEV short bf16cast(float f) {      // f32 -> bf16 bits (RNE via HW cvt)
  return (short)__builtin_bit_cast(unsigned short, (__bf16)f);
}
DEV unsigned cvt_pk_bf16(float a, float b) {  // a->low16, b->high16 (RNE)
  unsigned short lb = __builtin_bit_cast(unsigned short, (__bf16)a);
  unsigned short hb = __builtin_bit_cast(unsigned short, (__bf16)b);
  return (unsigned)lb | ((unsigned)hb << 16);
}
DEV unsigned pack_shorts(short a, short b) {
  return (unsigned)(unsigned short)a | ((unsigned)(unsigned short)b << 16);
}
DEV short8 cvt8(float4 a, float4 b) {   // 8 f32 -> short8 bf16
  union { short8 s; uint4 u; } r;
  r.u.x = cvt_pk_bf16(a.x, a.y); r.u.y = cvt_pk_bf16(a.z, a.w);
  r.u.z = cvt_pk_bf16(b.x, b.y); r.u.w = cvt_pk_bf16(b.z, b.w);
  return r.s;
}
DEV float fast_exp2(float x) {
#if __has_builtin(__builtin_amdgcn_exp2f)
  return __builtin_amdgcn_exp2f(x);
#else
  return exp2f(x);
#endif
}
// HW-verified (R3/R4): after op, a = [a.lo32, b.lo32], b = [a.hi32, b.hi32]
DEV void permswap32(unsigned& a, unsigned& b) {
  asm volatile("v_permlane32_swap_b32 %0, %1" : "+v"(a), "+v"(b));
}
// async global->LDS, 16B per lane; LDS dest = wave-uniform base + lane*16
DEV void gl_lds16(const short* g, short* l) {
  __builtin_amdgcn_global_load_lds(
      (const __attribute__((address_space(1))) void*)g,
      (__attribute__((address_space(3))) void*)l, 16, 0, 0);
}

// C[M][N] = sum_k A[m][k]*W[n][k]. 128xBN tile, BK=64, rows padded to 72
// shorts; reg-prefetch pipeline. A: f32 or bf16 (A_F32). B: ALWAYS f32.
// B pointer picked per block from {B0,B1,B2} by nbase>>9 (512-col segments).
template<bool A_F32, int BN, bool OUT_F32>
__global__ __launch_bounds__(256, 2) void gemm_bt(const void* __restrict__ Av,
                                                  const float* __restrict__ B0,
                                                  const float* __restrict__ B1,
                                                  const float* __restrict__ B2,
                                                  void* __restrict__ Cv,
                                                  int M, int N,
                                                  int qcols, float cscale) {
  constexpr int K = 512;                 // = W row stride
  constexpr int BG = BN / 32;            // B staging chunk-groups (4 or 2)
  constexpr int MT = (BN == 128) ? 4 : 2;
  constexpr int NT = 4;
  __shared__ __align__(16) short At[128 * 72];
  __shared__ __align__(16) short Bt[BN * 72];
  const int tid = threadIdx.x, lane = tid & 63, wv = tid >> 6;
  const int quad = lane >> 4, l16 = lane & 15;
  const int mbase = blockIdx.y * 128, nbase = blockIdx.x * BN;
  const int wr = (BN == 128) ? (wv >> 1) * 64 : wv * 32;
  const int wc = (BN == 128) ? (wv & 1) * 64 : 0;
  const float* Bsel = nbase < 512 ? B0 : (nbase < 1024 ? B1 : B2);
  const int col0 = nbase & 511;
  const float scale = (nbase < qcols) ? cscale : 1.0f;
  f32x4 acc[MT][NT] = {};
  float4 apf[4][2]; short8 aph[4];
  float4 bpf[BG][2];
#pragma unroll
  for (int i = 0; i < 4; i++) {                 // preload A, k0=0
    int flat = i * 256 + tid, row = flat >> 3, ch8 = (flat & 7) * 8;
    if (A_F32) {
      const float* Af = (const float*)Av;
      apf[i][0] = *(const float4*)&Af[(size_t)(mbase + row) * K + ch8];
      apf[i][1] = *(const float4*)&Af[(size_t)(mbase + row) * K + ch8 + 4];
    } else {
      aph[i] = *(const short8*)&((const short*)Av)[(size_t)(mbase + row) * K + ch8];
    }
  }
#pragma unroll
  for (int i = 0; i < BG; i++) {                // preload B (f32), k0=0
    int flat = i * 256 + tid, row = flat >> 3, ch8 = (flat & 7) * 8;
    bpf[i][0] = *(const float4*)&Bsel[(size_t)(col0 + row) * K + ch8];
    bpf[i][1] = *(const float4*)&Bsel[(size_t)(col0 + row) * K + ch8 + 4];
  }
  for (int k0 = 0; k0 < K; k0 += 64) {
    __syncthreads();
#pragma unroll
    for (int i = 0; i < 4; i++) {
      int flat = i * 256 + tid, row = flat >> 3, ch8 = (flat & 7) * 8;
      *(short8*)&At[row * 72 + ch8] = A_F32 ? cvt8(apf[i][0], apf[i][1]) : aph[i];
    }
#pragma unroll
    for (int i = 0; i < BG; i++) {
      int flat = i * 256 + tid, row = flat >> 3, ch8 = (flat & 7) * 8;
      *(short8*)&Bt[row * 72 + ch8] = cvt8(bpf[i][0], bpf[i][1]);
    }
    if (k0 + 64 < K) {
#pragma unroll
      for (int i = 0; i < 4; i++) {             // prefetch next A
        int flat = i * 256 + tid, row = flat >> 3, ch8 = (flat & 7) * 8;
        if (A_F32) {
          const float* Af = (const float*)Av;
          apf[i][0] = *(const float4*)&Af[(size_t)(mbase + row) * K + k0 + 64 + ch8];
          apf[i][1] = *(const float4*)&Af[(size_t)(mbase + row) * K + k0 + 64 + ch8 + 4];
        } else {
          aph[i] = *(const short8*)&((const short*)Av)[(size_t)(mbase + row) * K + k0 + 64 + ch8];
        }
      }
#pragma unroll
      for (int i = 0; i < BG; i++) {            // prefetch next B
        int flat = i * 256 + tid, row = flat >> 3, ch8 = (flat & 7) * 8;
        bpf[i][0] = *(const float4*)&Bsel[(size_t)(col0 + row) * K + k0 + 64 + ch8];
        bpf[i][1] = *(const float4*)&Bsel[(size_t)(col0 + row) * K + k0 + 64 + ch8 + 4];
      }
    }
    __syncthreads();
#pragma unroll
    for (int s = 0; s < 2; s++) {
      short8 af[MT], bf[NT];
#pragma unroll
      for (int t = 0; t < MT; t++)
        af[t] = *(short8*)&At[(wr + t * 16 + l16) * 72 + quad * 8 + s * 32];
#pragma unroll
      for (int t = 0; t < NT; t++)
        bf[t] = *(short8*)&Bt[(wc + t * 16 + l16) * 72 + quad * 8 + s * 32];
#pragma unroll
      for (int mt = 0; mt < MT; mt++)
#pragma unroll
        for (int nt = 0; nt < NT; nt++)
          acc[mt][nt] = __builtin_amdgcn_mfma_f32_16x16x32_bf16(af[mt], bf[nt], acc[mt][nt], 0, 0, 0);
    }
  }
#pragma unroll
  for (int mt = 0; mt < MT; mt++)
#pragma unroll
    for (int nt = 0; nt < NT; nt++)
#pragma unroll
      for (int r = 0; r < 4; r++) {             // C/D: row=quad*4+r, col=l16
        int row = mbase + wr + mt * 16 + quad * 4 + r;
        int col = nbase + wc + nt * 16 + l16;
        float v = acc[mt][nt][r] * scale;
        if (OUT_F32) ((float*)Cv)[(size_t)row * N + col] = v;
        else         ((short*)Cv)[(size_t)row * N + col] = bf16cast(v);
      }
}

// Flash attention. S^T form, BM=128, 256 thr = 4 waves x 32 q-rows.
// TWO 64-key tiles per barrier period (16 periods), 4-buffer LDS rotation:
// period p computes tiles {2p,2p+1} from buffer pair (p&1)*2, stages tiles
// {2p+2,2p+3} into the other pair (K via gl_lds, V via regs). Math/layouts
// identical to R8 (verified): swizzle chunk^(row&7), in-register P, exp2
// softmax with mask C-init + late bias, MFMA rowsum, setprio on MFMA.
__global__ __launch_bounds__(256, 2) void attn_kernel(const short* __restrict__ QKV,
                                                      const float* __restrict__ bias,
                                                      const void* __restrict__ mask,
                                                      short* __restrict__ Aout) {
  __shared__ __align__(16) short Kt[4][64 * 64];     // [key][hd], 4-buf, swizzled
  __shared__ __align__(16) short Vt[4][64 * 64];     // [hd][key_perm], 4-buf, swizzled
  __shared__ __align__(16) float mlds[Nc];
  __shared__ int mflag;
  const int tid = threadIdx.x, lane = tid & 63, wv = tid >> 6;   // wv 0..3
  const int quad = lane >> 4, l16 = lane & 15;
  const int qt = blockIdx.x & 15, h = (blockIdx.x >> 4) & 7, b = (int)(blockIdx.x >> 7);
  const int qrow0 = qt * 128;
  const int q0 = qrow0 + wv * 32 + l16;              // n=0 q-row; n=1 is q0+16
  const float* biasq0 = bias + ((size_t)b * Nc + q0) * Nc;
  const float* biasq1 = biasq0 + (size_t)16 * Nc;
  const short* Kbase = QKV + Dc + h * HDc;
  const short* Vbase = QKV + 2 * Dc + h * HDc;

  // ---- issue K gl_lds for tiles 0,1 immediately (ages through prologue) ----
#pragma unroll
  for (int j = 0; j < 2; j++)
#pragma unroll
    for (int g = 0; g < 2; g++) {
      int seg = wv * 2 + g, c = seg * 64 + lane;
      int row = c >> 3, ch = c & 7;
      gl_lds16(&Kbase[(size_t)(b * Nc + j * 64 + row) * QKVNc + ((ch ^ (row & 7)) << 3)],
               &Kt[j][seg * 512]);
    }

  short8 qf[2][2];  // [n][s]: Q (pre-scaled 0.125*log2e), q=n*16+l16, k=quad*8+32s+j
  {
    const short* qp0 = QKV + (size_t)(b * Nc + q0) * QKVNc + h * HDc + quad * 8;
    qf[0][0] = *(const short8*)qp0;
    qf[0][1] = *(const short8*)(qp0 + 32);
    const short* qp1 = qp0 + (size_t)16 * QKVNc;
    qf[1][0] = *(const short8*)qp1;
    qf[1][1] = *(const short8*)(qp1 + 32);
  }

  // V staging assignment (reg-staged: needs transpose+pack, gl_lds can't)
  const int vp = tid & 31, vq = tid >> 5;            // V: key-pair, hd-oct 0..7
  const int vperm = (vp & 25) | ((vp & 4) >> 1) | ((vp & 2) << 1);  // key bits 3<->2
  const int vwbase = (((vperm >> 2)) << 3) + 2 * (vperm & 3);

  short8 v0pre[2], v1pre[2];                         // [tile-slot]
  float4 bpre[2][2][4];                              // [tile-slot][n][t]
#pragma unroll
  for (int j = 0; j < 2; j++) {
    v0pre[j] = *(const short8*)&Vbase[(size_t)(b * Nc + j * 64 + 2 * vp) * QKVNc + vq * 8];
    v1pre[j] = *(const short8*)&Vbase[(size_t)(b * Nc + j * 64 + 2 * vp + 1) * QKVNc + vq * 8];
#pragma unroll
    for (int t = 0; t < 4; t++) {
      bpre[j][0][t] = *(const float4*)&biasq0[j * 64 + t * 16 + quad * 4];
      bpre[j][1][t] = *(const float4*)&biasq1[j * 64 + t * 16 + quad * 4];
    }
  }

  // ---- inline mask convert: detect dtype on this b's slice, fill mlds ----
  if (tid == 0) mflag = 0;
  __syncthreads();
  {
    const uchar4* mw = (const uchar4*)((const char*)mask + (size_t)b * 2048);
    int acc = 0;
#pragma unroll
    for (int i = tid; i < 512; i += 256) {
      uchar4 v = mw[i];
      acc |= (int)v.y | (int)v.z | (int)v.w;
    }
    if (acc) atomicOr(&mflag, 1);
  }
  __syncthreads();
  {
    int isbyte = mflag;
    const unsigned char* mb = (const unsigned char*)mask + (size_t)b * 2048;
    const int* mi = (const int*)mask + (size_t)b * 2048;
    for (int i = tid; i < Nc; i += 256) {
      int v = isbyte ? (int)mb[i] : mi[i];
      mlds[i] = v ? -1e30f : 0.0f;
    }
  }

  const short ONEB = (short)0x3F80;                  // bf16 1.0
  const short8 ones = { ONEB, ONEB, ONEB, ONEB, ONEB, ONEB, ONEB, ONEB };

  f32x4 oacc[2][4] = {};                             // [m][t]: row q=m*16+quad*4+r, col hd=16t+l16
  f32x4 sumacc[2] = {};                              // rowsum per m-tile

  for (int pd = 0; pd < 16; pd++) {
    const int pb = (pd & 1) * 2;                     // current buffer pair
    const int nb = 2 - pb;                           // next buffer pair

    // W: V regs -> Vt[pb+j] (swizzled); Kt[pb+j] filled by gl_lds last period
#pragma unroll
    for (int j = 0; j < 2; j++)
#pragma unroll
      for (int jj = 0; jj < 8; jj++) {
        int hd = vq * 8 + jj;
        *(unsigned*)&Vt[pb + j][hd * 64 + (vwbase ^ ((hd & 7) << 3))] =
            pack_shorts(v0pre[j][jj], v1pre[j][jj]);
      }
    __syncthreads();                                 // ONE barrier per 2 tiles

    // L: issue next pair: K via gl_lds -> Kt[nb+j]; V via regs
#pragma unroll
    for (int j = 0; j < 2; j++) {
      const int kn = ((2 * pd + 2 + j) & 31) * 64;   // wraps, in-bounds
#pragma unroll
      for (int g = 0; g < 2; g++) {
        int seg = wv * 2 + g, c = seg * 64 + lane;
        int row = c >> 3, ch = c & 7;
        gl_lds16(&Kbase[(size_t)(b * Nc + kn + row) * QKVNc + ((ch ^ (row & 7)) << 3)],
                 &Kt[nb + j][seg * 512]);
      }
      v0pre[j] = *(const short8*)&Vbase[(size_t)(b * Nc + kn + 2 * vp) * QKVNc + vq * 8];
      v1pre[j] = *(const short8*)&Vbase[(size_t)(b * Nc + kn + 2 * vp + 1) * QKVNc + vq * 8];
    }

    // C: two independent tile-chains; unrolled so the scheduler can overlap
    // tile A's VALU (softmax) with tile B's MFMA and vice versa.
#pragma unroll
    for (int j = 0; j < 2; j++) {
      const int kb = (2 * pd + j) * 64;
      const int knb = ((2 * pd + j + 2) & 31) * 64;

      // C-init = mask (broadcast LDS reads; same for both n-tiles)
      f32x4 sacc[2][4];
#pragma unroll
      for (int t = 0; t < 4; t++) {
        float4 mv = *(const float4*)&mlds[kb + t * 16 + quad * 4];
        sacc[0][t][0] = mv.x; sacc[0][t][1] = mv.y; sacc[0][t][2] = mv.z; sacc[0][t][3] = mv.w;
        sacc[1][t] = sacc[0][t];
      }

      // QK^T: S^T[key=16t+4quad+r][q=n*16+l16]; kf shared across n
      __builtin_amdgcn_s_setprio(1);
#pragma unroll
      for (int s = 0; s < 2; s++)
#pragma unroll
        for (int t = 0; t < 4; t++) {
          short8 kf = *(short8*)&Kt[pb + j][(t * 16 + l16) * 64 + (((quad + 4 * s) ^ (l16 & 7)) << 3)];
          sacc[0][t] = __builtin_amdgcn_mfma_f32_16x16x32_bf16(kf, qf[0][s], sacc[0][t], 0, 0, 0);
          sacc[1][t] = __builtin_amdgcn_mfma_f32_16x16x32_bf16(kf, qf[1][s], sacc[1][t], 0, 0, 0);
        }
      __builtin_amdgcn_s_setprio(0);

      // softmax: p = exp2(bias*log2e + s_with_mask); consumes bpre[j]
      short8 pf[2][2];
#pragma unroll
      for (int n = 0; n < 2; n++) {
        unsigned pw[4][2];
#pragma unroll
        for (int t = 0; t < 4; t++) {
          float p0 = fast_exp2(__builtin_fmaf(bpre[j][n][t].x, L2E, sacc[n][t][0]));
          float p1 = fast_exp2(__builtin_fmaf(bpre[j][n][t].y, L2E, sacc[n][t][1]));
          float p2 = fast_exp2(__builtin_fmaf(bpre[j][n][t].z, L2E, sacc[n][t][2]));
          float p3 = fast_exp2(__builtin_fmaf(bpre[j][n][t].w, L2E, sacc[n][t][3]));
          pw[t][0] = cvt_pk_bf16(p0, p1);
          pw[t][1] = cvt_pk_bf16(p2, p3);
        }
        permswap32(pw[0][0], pw[1][0]); permswap32(pw[0][1], pw[1][1]);
        permswap32(pw[2][0], pw[3][0]); permswap32(pw[2][1], pw[3][1]);
        union { unsigned u[4]; short8 s; }
            a0{{pw[0][0], pw[0][1], pw[1][0], pw[1][1]}},
            a1{{pw[2][0], pw[2][1], pw[3][0], pw[3][1]}};
        pf[n][0] = a0.s; pf[n][1] = a1.s;
      }

      // bias prefetch for this slot's tile of the next period (late issue)
#pragma unroll
      for (int t = 0; t < 4; t++) {
        bpre[j][0][t] = *(const float4*)&biasq0[knb + t * 16 + quad * 4];
        bpre[j][1][t] = *(const float4*)&biasq1[knb + t * 16 + quad * 4];
      }

      // PV: O += P·V (permuted contraction, matches Vt layout); rowsum += P·1
      __builtin_amdgcn_s_setprio(1);
#pragma unroll
      for (int s = 0; s < 2; s++) {
        sumacc[0] = __builtin_amdgcn_mfma_f32_16x16x32_bf16(pf[0][s], ones, sumacc[0], 0, 0, 0);
        sumacc[1] = __builtin_amdgcn_mfma_f32_16x16x32_bf16(pf[1][s], ones, sumacc[1], 0, 0, 0);
#pragma unroll
        for (int t = 0; t < 4; t++) {
          short8 vf = *(short8*)&Vt[pb + j][(t * 16 + l16) * 64 + (((quad + 4 * s) ^ (l16 & 7)) << 3)];
          oacc[0][t] = __builtin_amdgcn_mfma_f32_16x16x32_bf16(pf[0][s], vf, oacc[0][t], 0, 0, 0);
          oacc[1][t] = __builtin_amdgcn_mfma_f32_16x16x32_bf16(pf[1][s], vf, oacc[1][t], 0, 0, 0);
        }
      }
      __builtin_amdgcn_s_setprio(0);
    }
  }

#pragma unroll
  for (int m = 0; m < 2; m++)
#pragma unroll
    for (int r = 0; r < 4; r++) {                    // O row q=m*16+quad*4+r, col hd=16t+l16
      float inv = 1.0f / sumacc[m][r];
      int row = b * Nc + qrow0 + wv * 32 + m * 16 + quad * 4 + r;
#pragma unroll
      for (int t = 0; t < 4; t++)
        Aout[(size_t)row * Dc + h * HDc + t * 16 + l16] = bf16cast(oacc[m][t][r] * inv);
    }
}

extern "C" void kernel_launch(void* const* d_in, const int* in_sizes, int n_in,
                              void* d_out, int out_size, void* d_ws, size_t ws_size,
                              hipStream_t stream) {
  const float* q    = (const float*)d_in[0];
  const void*  mask = d_in[1];
  const float* bias = (const float*)d_in[2];
  const float* Wq   = (const float*)d_in[3];
  const float* Wk   = (const float*)d_in[4];
  const float* Wv   = (const float*)d_in[5];
  const float* Wo   = (const float*)d_in[6];
  float* out = (float*)d_out;

  char* ws = (char*)d_ws;
  short* QKV  = (short*)ws;  ws += (size_t)Mc * QKVNc * 2;
  short* aout = (short*)ws;  ws += (size_t)Mc * Dc * 2;

  // QKV = q @ [Wq|Wk|Wv]^T, all conversion in-staging; Q cols scaled 0.125*L2E.
  gemm_bt<true, 128, false><<<dim3(QKVNc / 128, Mc / 128), dim3(256), 0, stream>>>(
      (const void*)q, Wq, Wk, Wv, (void*)QKV, Mc, QKVNc, Dc, 0.125f * L2E);
  attn_kernel<<<dim3(Bc * Hc * 16), dim3(256), 0, stream>>>(QKV, bias, mask, aout);
  gemm_bt<false, 64, true><<<dim3(Dc / 64, Mc / 128), dim3(256), 0, stream>>>(
      (const void*)aout, Wo, Wo, Wo, (void*)out, Mc, Dc, 0, 1.0f);
}

// Round 10
// 244.358 us; speedup vs baseline: 1.4394x; 1.0156x over previous
//
#include <hip/hip_runtime.h>
#include <stdint.h>

// MultiHeadAttentionProj: B=4, N=2048, D=512, H=8, HD=64
// FOUR launches:
//  cvtw    : Wq,Wk,Wv -> Wqkv (bf16 concat), Wo -> Wob (bf16). ~3 us.
//  gemm_qkv: QKV = q @ Wqkv^T. BN=192 (grid 512 = 2/CU, NO tail round).
//    A = q f32, reg-staged + cvt (pitch-72 LDS). B = Wqkv bf16 via
//    DOUBLE-BUFFERED global_load_lds. Barrier (a) = __syncthreads (full
//    drain — loads aged through prior compute); barrier (b) = lgkm-ONLY
//    (s_waitcnt lgkmcnt(0); s_barrier) so B gl_lds + A prefetch issued in
//    the (a)..(b) window stay in flight across it and age through compute.
//    Q cols (<512) scaled 0.125*log2e per-nt in epilogue.
//  attn    : FROZEN byte-identical to R9 (verified, 109 us).
//  gemm_out: out = aout @ Wob^T. BN=64, pure gl_lds, double-buffered LDS,
//    ONE full-drain barrier per K-step (loads age through compute).

typedef __attribute__((ext_vector_type(8))) short short8;
typedef __attribute__((ext_vector_type(4))) short short4v;
typedef __attribute__((ext_vector_type(4))) float f32x4;

#define DEV static __device__ __forceinline__

constexpr int Bc = 4, Nc = 2048, Dc = 512, Hc = 8, HDc = 64;
constexpr int Mc = Bc * Nc;        // 8192 rows
constexpr int QKVNc = 3 * Dc;      // 1536
constexpr float L2E = 1.44269504f;

DEV short bf16cast(float f) {      // f32 -> bf16 bits (RNE via HW cvt)
  return (short)__builtin_bit_cast(unsigned short, (__bf16)f);
}
DEV unsigned cvt_pk_bf16(float a, float b) {  // a->low16, b->high16 (RNE)
  unsigned short lb = __builtin_bit_cast(unsigned short, (__bf16)a);
  unsigned short hb = __builtin_bit_cast(unsigned short, (__bf16)b);
  return (unsigned)lb | ((unsigned)hb << 16);
}
DEV unsigned pack_shorts(short a, short b) {
  return (unsigned)(unsigned short)a | ((unsigned)(unsigned short)b << 16);
}
DEV short8 cvt8(float4 a, float4 b) {   // 8 f32 -> short8 bf16
  union { short8 s; uint4 u; } r;
  r.u.x = cvt_pk_bf16(a.x, a.y); r.u.y = cvt_pk_bf16(a.z, a.w);
  r.u.z = cvt_pk_bf16(b.x, b.y); r.u.w = cvt_pk_bf16(b.z, b.w);
  return r.s;
}
DEV float fast_exp2(float x) {
#if __has_builtin(__builtin_amdgcn_exp2f)
  return __builtin_amdgcn_exp2f(x);
#else
  return exp2f(x);
#endif
}
// HW-verified (R3/R4): after op, a = [a.lo32, b.lo32], b = [a.hi32, b.hi32]
DEV void permswap32(unsigned& a, unsigned& b) {
  asm volatile("v_permlane32_swap_b32 %0, %1" : "+v"(a), "+v"(b));
}
// async global->LDS, 16B per lane; LDS dest = wave-uniform base + lane*16
DEV void gl_lds16(const short* g, short* l) {
  __builtin_amdgcn_global_load_lds(
      (const __attribute__((address_space(1))) void*)g,
      (__attribute__((address_space(3))) void*)l, 16, 0, 0);
}
// barrier WITHOUT vmcnt drain: LDS writes visible, vmem loads stay in flight
DEV void barrier_lgkm_only() {
  asm volatile("s_waitcnt lgkmcnt(0)" ::: "memory");
  __builtin_amdgcn_s_barrier();
  __builtin_amdgcn_sched_barrier(0);
}

// Wq,Wk,Wv -> Wqkv (bf16 concat rows), Wo -> Wob. 1024 blocks x 256 thr.
__global__ void cvtw_kernel(const float* __restrict__ Wq, const float* __restrict__ Wk,
                            const float* __restrict__ Wv, const float* __restrict__ Wo,
                            short* __restrict__ Wqkv, short* __restrict__ Wob) {
  int which = blockIdx.x >> 8;                       // 4 x 256 blocks
  int j = (blockIdx.x & 255) * 256 + threadIdx.x;    // float4 index < 65536
  const float* src = which == 0 ? Wq : which == 1 ? Wk : which == 2 ? Wv : Wo;
  short* dst = (which == 3) ? Wob : Wqkv + which * (Dc * Dc);
  float4 v = ((const float4*)src)[j];
  short4v o = { bf16cast(v.x), bf16cast(v.y), bf16cast(v.z), bf16cast(v.w) };
  ((short4v*)dst)[j] = o;
}

// QKV[M][1536] = q[M][512] @ Wqkv[1536][512]^T. 128x192 tiles, BK=64.
// A: f32 reg-staged+cvt into At (pitch 72, single buffer).
// B: gl_lds into Bt (pitch 64, dbuf, pre-swizzled source chunk^=(row&7)).
__global__ __launch_bounds__(256, 2) void gemm_qkv(const float* __restrict__ q,
                                                   const short* __restrict__ Wqkv,
                                                   short* __restrict__ QKV,
                                                   float cscale) {
  constexpr int K = 512;
  __shared__ __align__(16) short At[128 * 72];
  __shared__ __align__(16) short Bt[2][192 * 64];
  const int tid = threadIdx.x, lane = tid & 63, wv = tid >> 6;
  const int quad = lane >> 4, l16 = lane & 15;
  const int mbase = blockIdx.y * 128, nbase = blockIdx.x * 192;
  const int wr = (wv >> 1) * 64, wc = (wv & 1) * 96;
  f32x4 acc[4][6] = {};
  float4 apf[4][2];
#pragma unroll
  for (int i = 0; i < 4; i++) {                 // preload A regs, k0=0
    int flat = i * 256 + tid, row = flat >> 3, ch8 = (flat & 7) * 8;
    apf[i][0] = *(const float4*)&q[(size_t)(mbase + row) * K + ch8];
    apf[i][1] = *(const float4*)&q[(size_t)(mbase + row) * K + ch8 + 4];
  }
#pragma unroll
  for (int i = 0; i < 6; i++) {                 // issue B gl_lds, k0=0 -> Bt[0]
    int ibase = (wv * 6 + i) * 64;
    int row = (ibase + lane) >> 3, ch = lane & 7;
    gl_lds16(&Wqkv[(size_t)(nbase + row) * K + ((ch ^ (row & 7)) << 3)],
             &Bt[0][ibase << 3]);
  }
  for (int k0 = 0; k0 < K; k0 += 64) {
    const int cur = (k0 >> 6) & 1;
    __syncthreads();                            // (a) full drain: Bt[cur]+apf ready
#pragma unroll
    for (int i = 0; i < 4; i++) {               // At <- cvt(apf)
      int flat = i * 256 + tid, row = flat >> 3, ch8 = (flat & 7) * 8;
      *(short8*)&At[row * 72 + ch8] = cvt8(apf[i][0], apf[i][1]);
    }
    if (k0 + 64 < K) {                          // issue next B + prefetch next A
#pragma unroll
      for (int i = 0; i < 6; i++) {
        int ibase = (wv * 6 + i) * 64;
        int row = (ibase + lane) >> 3, ch = lane & 7;
        gl_lds16(&Wqkv[(size_t)(nbase + row) * K + k0 + 64 + ((ch ^ (row & 7)) << 3)],
                 &Bt[cur ^ 1][ibase << 3]);
      }
#pragma unroll
      for (int i = 0; i < 4; i++) {
        int flat = i * 256 + tid, row = flat >> 3, ch8 = (flat & 7) * 8;
        apf[i][0] = *(const float4*)&q[(size_t)(mbase + row) * K + k0 + 64 + ch8];
        apf[i][1] = *(const float4*)&q[(size_t)(mbase + row) * K + k0 + 64 + ch8 + 4];
      }
    }
    barrier_lgkm_only();                        // (b) At visible; loads stay in flight
#pragma unroll
    for (int s = 0; s < 2; s++) {
      short8 af[4], bf[6];
#pragma unroll
      for (int t = 0; t < 4; t++)
        af[t] = *(short8*)&At[(wr + t * 16 + l16) * 72 + quad * 8 + s * 32];
#pragma unroll
      for (int t = 0; t < 6; t++) {
        int r = wc + t * 16 + l16;
        bf[t] = *(short8*)&Bt[cur][r * 64 + (((quad + 4 * s) ^ (r & 7)) << 3)];
      }
#pragma unroll
      for (int mt = 0; mt < 4; mt++)
#pragma unroll
        for (int nt = 0; nt < 6; nt++)
          acc[mt][nt] = __builtin_amdgcn_mfma_f32_16x16x32_bf16(af[mt], bf[nt], acc[mt][nt], 0, 0, 0);
    }
  }
#pragma unroll
  for (int nt = 0; nt < 6; nt++) {
    const float sc = (nbase + wc + nt * 16 < 512) ? cscale : 1.0f;  // 16-col groups never straddle 512
#pragma unroll
    for (int mt = 0; mt < 4; mt++)
#pragma unroll
      for (int r = 0; r < 4; r++) {             // C/D: row=quad*4+r, col=l16
        int row = mbase + wr + mt * 16 + quad * 4 + r;
        int col = nbase + wc + nt * 16 + l16;
        QKV[(size_t)row * QKVNc + col] = bf16cast(acc[mt][nt][r] * sc);
      }
  }
}

// out[M][512] = aout[M][512] @ Wob[512][512]^T. 128x64 tiles, BK=64.
// Pure gl_lds, dbuf LDS, ONE full-drain barrier per step (loads issued after
// the barrier age through the whole compute phase).
__global__ __launch_bounds__(256, 2) void gemm_out(const short* __restrict__ aout,
                                                   const short* __restrict__ Wob,
                                                   float* __restrict__ out) {
  constexpr int K = 512;
  __shared__ __align__(16) short At[2][128 * 64];
  __shared__ __align__(16) short Bt[2][64 * 64];
  const int tid = threadIdx.x, lane = tid & 63, wv = tid >> 6;
  const int quad = lane >> 4, l16 = lane & 15;
  const int mbase = blockIdx.y * 128, nbase = blockIdx.x * 64;
  const int wr = wv * 32;
  f32x4 acc[2][4] = {};
#pragma unroll
  for (int i = 0; i < 4; i++) {                 // issue A gl_lds, k0=0 -> At[0]
    int ibase = (wv * 4 + i) * 64;
    int row = (ibase + lane) >> 3, ch = lane & 7;
    gl_lds16(&aout[(size_t)(mbase + row) * K + ((ch ^ (row & 7)) << 3)],
             &At[0][ibase << 3]);
  }
#pragma unroll
  for (int i = 0; i < 2; i++) {                 // issue B gl_lds, k0=0 -> Bt[0]
    int ibase = (wv * 2 + i) * 64;
    int row = (ibase + lane) >> 3, ch = lane & 7;
    gl_lds16(&Wob[(size_t)(nbase + row) * K + ((ch ^ (row & 7)) << 3)],
             &Bt[0][ibase << 3]);
  }
  for (int k0 = 0; k0 < K; k0 += 64) {
    const int cur = (k0 >> 6) & 1;
    __syncthreads();                            // buf[cur] ready (aged); prev reads done
    if (k0 + 64 < K) {                          // issue next tile -> buf[cur^1]
#pragma unroll
      for (int i = 0; i < 4; i++) {
        int ibase = (wv * 4 + i) * 64;
        int row = (ibase + lane) >> 3, ch = lane & 7;
        gl_lds16(&aout[(size_t)(mbase + row) * K + k0 + 64 + ((ch ^ (row & 7)) << 3)],
                 &At[cur ^ 1][ibase << 3]);
      }
#pragma unroll
      for (int i = 0; i < 2; i++) {
        int ibase = (wv * 2 + i) * 64;
        int row = (ibase + lane) >> 3, ch = lane & 7;
        gl_lds16(&Wob[(size_t)(nbase + row) * K + k0 + 64 + ((ch ^ (row & 7)) << 3)],
                 &Bt[cur ^ 1][ibase << 3]);
      }
    }
#pragma unroll
    for (int s = 0; s < 2; s++) {
      short8 af[2], bf[4];
#pragma unroll
      for (int t = 0; t < 2; t++) {
        int r = wr + t * 16 + l16;
        af[t] = *(short8*)&At[cur][r * 64 + (((quad + 4 * s) ^ (r & 7)) << 3)];
      }
#pragma unroll
      for (int t = 0; t < 4; t++) {
        int r = t * 16 + l16;
        bf[t] = *(short8*)&Bt[cur][r * 64 + (((quad + 4 * s) ^ (r & 7)) << 3)];
      }
#pragma unroll
      for (int mt = 0; mt < 2; mt++)
#pragma unroll
        for (int nt = 0; nt < 4; nt++)
          acc[mt][nt] = __builtin_amdgcn_mfma_f32_16x16x32_bf16(af[mt], bf[nt], acc[mt][nt], 0, 0, 0);
    }
  }
#pragma unroll
  for (int mt = 0; mt < 2; mt++)
#pragma unroll
    for (int nt = 0; nt < 4; nt++)
#pragma unroll
      for (int r = 0; r < 4; r++) {             // C/D: row=quad*4+r, col=l16
        int row = mbase + wr + mt * 16 + quad * 4 + r;
        int col = nbase + nt * 16 + l16;
        out[(size_t)row * Dc + col] = acc[mt][nt][r];
      }
}

// Flash attention — FROZEN byte-identical to R9 (verified, 109 us).
__global__ __launch_bounds__(256, 2) void attn_kernel(const short* __restrict__ QKV,
                                                      const float* __restrict__ bias,
                                                      const void* __restrict__ mask,
                                                      short* __restrict__ Aout) {
  __shared__ __align__(16) short Kt[4][64 * 64];     // [key][hd], 4-buf, swizzled
  __shared__ __align__(16) short Vt[4][64 * 64];     // [hd][key_perm], 4-buf, swizzled
  __shared__ __align__(16) float mlds[Nc];
  __shared__ int mflag;
  const int tid = threadIdx.x, lane = tid & 63, wv = tid >> 6;   // wv 0..3
  const int quad = lane >> 4, l16 = lane & 15;
  const int qt = blockIdx.x & 15, h = (blockIdx.x >> 4) & 7, b = (int)(blockIdx.x >> 7);
  const int qrow0 = qt * 128;
  const int q0 = qrow0 + wv * 32 + l16;              // n=0 q-row; n=1 is q0+16
  const float* biasq0 = bias + ((size_t)b * Nc + q0) * Nc;
  const float* biasq1 = biasq0 + (size_t)16 * Nc;
  const short* Kbase = QKV + Dc + h * HDc;
  const short* Vbase = QKV + 2 * Dc + h * HDc;

  // ---- issue K gl_lds for tiles 0,1 immediately (ages through prologue) ----
#pragma unroll
  for (int j = 0; j < 2; j++)
#pragma unroll
    for (int g = 0; g < 2; g++) {
      int seg = wv * 2 + g, c = seg * 64 + lane;
      int row = c >> 3, ch = c & 7;
      gl_lds16(&Kbase[(size_t)(b * Nc + j * 64 + row) * QKVNc + ((ch ^ (row & 7)) << 3)],
               &Kt[j][seg * 512]);
    }

  short8 qf[2][2];  // [n][s]: Q (pre-scaled 0.125*log2e), q=n*16+l16, k=quad*8+32s+j
  {
    const short* qp0 = QKV + (size_t)(b * Nc + q0) * QKVNc + h * HDc + quad * 8;
    qf[0][0] = *(const short8*)qp0;
    qf[0][1] = *(const short8*)(qp0 + 32);
    const short* qp1 = qp0 + (size_t)16 * QKVNc;
    qf[1][0] = *(const short8*)qp1;
    qf[1][1] = *(const short8*)(qp1 + 32);
  }

  // V staging assignment (reg-staged: needs transpose+pack, gl_lds can't)
  const int vp = tid & 31, vq = tid >> 5;            // V: key-pair, hd-oct 0..7
  const int vperm = (vp & 25) | ((vp & 4) >> 1) | ((vp & 2) << 1);  // key bits 3<->2
  const int vwbase = (((vperm >> 2)) << 3) + 2 * (vperm & 3);

  short8 v0pre[2], v1pre[2];                         // [tile-slot]
  float4 bpre[2][2][4];                              // [tile-slot][n][t]
#pragma unroll
  for (int j = 0; j < 2; j++) {
    v0pre[j] = *(const short8*)&Vbase[(size_t)(b * Nc + j * 64 + 2 * vp) * QKVNc + vq * 8];
    v1pre[j] = *(const short8*)&Vbase[(size_t)(b * Nc + j * 64 + 2 * vp + 1) * QKVNc + vq * 8];
#pragma unroll
    for (int t = 0; t < 4; t++) {
      bpre[j][0][t] = *(const float4*)&biasq0[j * 64 + t * 16 + quad * 4];
      bpre[j][1][t] = *(const float4*)&biasq1[j * 64 + t * 16 + quad * 4];
    }
  }

  // ---- inline mask convert: detect dtype on this b's slice, fill mlds ----
  if (tid == 0) mflag = 0;
  __syncthreads();
  {
    const uchar4* mw = (const uchar4*)((const char*)mask + (size_t)b * 2048);
    int acc = 0;
#pragma unroll
    for (int i = tid; i < 512; i += 256) {
      uchar4 v = mw[i];
      acc |= (int)v.y | (int)v.z | (int)v.w;
    }
    if (acc) atomicOr(&mflag, 1);
  }
  __syncthreads();
  {
    int isbyte = mflag;
    const unsigned char* mb = (const unsigned char*)mask + (size_t)b * 2048;
    const int* mi = (const int*)mask + (size_t)b * 2048;
    for (int i = tid; i < Nc; i += 256) {
      int v = isbyte ? (int)mb[i] : mi[i];
      mlds[i] = v ? -1e30f : 0.0f;
    }
  }

  const short ONEB = (short)0x3F80;                  // bf16 1.0
  const short8 ones = { ONEB, ONEB, ONEB, ONEB, ONEB, ONEB, ONEB, ONEB };

  f32x4 oacc[2][4] = {};                             // [m][t]: row q=m*16+quad*4+r, col hd=16t+l16
  f32x4 sumacc[2] = {};                              // rowsum per m-tile

  for (int pd = 0; pd < 16; pd++) {
    const int pb = (pd & 1) * 2;                     // current buffer pair
    const int nb = 2 - pb;                           // next buffer pair

    // W: V regs -> Vt[pb+j] (swizzled); Kt[pb+j] filled by gl_lds last period
#pragma unroll
    for (int j = 0; j < 2; j++)
#pragma unroll
      for (int jj = 0; jj < 8; jj++) {
        int hd = vq * 8 + jj;
        *(unsigned*)&Vt[pb + j][hd * 64 + (vwbase ^ ((hd & 7) << 3))] =
            pack_shorts(v0pre[j][jj], v1pre[j][jj]);
      }
    __syncthreads();                                 // ONE barrier per 2 tiles

    // L: issue next pair: K via gl_lds -> Kt[nb+j]; V via regs
#pragma unroll
    for (int j = 0; j < 2; j++) {
      const int kn = ((2 * pd + 2 + j) & 31) * 64;   // wraps, in-bounds
#pragma unroll
      for (int g = 0; g < 2; g++) {
        int seg = wv * 2 + g, c = seg * 64 + lane;
        int row = c >> 3, ch = c & 7;
        gl_lds16(&Kbase[(size_t)(b * Nc + kn + row) * QKVNc + ((ch ^ (row & 7)) << 3)],
                 &Kt[nb + j][seg * 512]);
      }
      v0pre[j] = *(const short8*)&Vbase[(size_t)(b * Nc + kn + 2 * vp) * QKVNc + vq * 8];
      v1pre[j] = *(const short8*)&Vbase[(size_t)(b * Nc + kn + 2 * vp + 1) * QKVNc + vq * 8];
    }

    // C: two independent tile-chains; unrolled so the scheduler can overlap
    // tile A's VALU (softmax) with tile B's MFMA and vice versa.
#pragma unroll
    for (int j = 0; j < 2; j++) {
      const int kb = (2 * pd + j) * 64;
      const int knb = ((2 * pd + j + 2) & 31) * 64;

      // C-init = mask (broadcast LDS reads; same for both n-tiles)
      f32x4 sacc[2][4];
#pragma unroll
      for (int t = 0; t < 4; t++) {
        float4 mv = *(const float4*)&mlds[kb + t * 16 + quad * 4];
        sacc[0][t][0] = mv.x; sacc[0][t][1] = mv.y; sacc[0][t][2] = mv.z; sacc[0][t][3] = mv.w;
        sacc[1][t] = sacc[0][t];
      }

      // QK^T: S^T[key=16t+4quad+r][q=n*16+l16]; kf shared across n
      __builtin_amdgcn_s_setprio(1);
#pragma unroll
      for (int s = 0; s < 2; s++)
#pragma unroll
        for (int t = 0; t < 4; t++) {
          short8 kf = *(short8*)&Kt[pb + j][(t * 16 + l16) * 64 + (((quad + 4 * s) ^ (l16 & 7)) << 3)];
          sacc[0][t] = __builtin_amdgcn_mfma_f32_16x16x32_bf16(kf, qf[0][s], sacc[0][t], 0, 0, 0);
          sacc[1][t] = __builtin_amdgcn_mfma_f32_16x16x32_bf16(kf, qf[1][s], sacc[1][t], 0, 0, 0);
        }
      __builtin_amdgcn_s_setprio(0);

      // softmax: p = exp2(bias*log2e + s_with_mask); consumes bpre[j]
      short8 pf[2][2];
#pragma unroll
      for (int n = 0; n < 2; n++) {
        unsigned pw[4][2];
#pragma unroll
        for (int t = 0; t < 4; t++) {
          float p0 = fast_exp2(__builtin_fmaf(bpre[j][n][t].x, L2E, sacc[n][t][0]));
          float p1 = fast_exp2(__builtin_fmaf(bpre[j][n][t].y, L2E, sacc[n][t][1]));
          float p2 = fast_exp2(__builtin_fmaf(bpre[j][n][t].z, L2E, sacc[n][t][2]));
          float p3 = fast_exp2(__builtin_fmaf(bpre[j][n][t].w, L2E, sacc[n][t][3]));
          pw[t][0] = cvt_pk_bf16(p0, p1);
          pw[t][1] = cvt_pk_bf16(p2, p3);
        }
        permswap32(pw[0][0], pw[1][0]); permswap32(pw[0][1], pw[1][1]);
        permswap32(pw[2][0], pw[3][0]); permswap32(pw[2][1], pw[3][1]);
        union { unsigned u[4]; short8 s; }
            a0{{pw[0][0], pw[0][1], pw[1][0], pw[1][1]}},
            a1{{pw[2][0], pw[2][1], pw[3][0], pw[3][1]}};
        pf[n][0] = a0.s; pf[n][1] = a1.s;
      }

      // bias prefetch for this slot's tile of the next period (late issue)
#pragma unroll
      for (int t = 0; t < 4; t++) {
        bpre[j][0][t] = *(const float4*)&biasq0[knb + t * 16 + quad * 4];
        bpre[j][1][t] = *(const float4*)&biasq1[knb + t * 16 + quad * 4];
      }

      // PV: O += P·V (permuted contraction, matches Vt layout); rowsum += P·1
      __builtin_amdgcn_s_setprio(1);
#pragma unroll
      for (int s = 0; s < 2; s++) {
        sumacc[0] = __builtin_amdgcn_mfma_f32_16x16x32_bf16(pf[0][s], ones, sumacc[0], 0, 0, 0);
        sumacc[1] = __builtin_amdgcn_mfma_f32_16x16x32_bf16(pf[1][s], ones, sumacc[1], 0, 0, 0);
#pragma unroll
        for (int t = 0; t < 4; t++) {
          short8 vf = *(short8*)&Vt[pb + j][(t * 16 + l16) * 64 + (((quad + 4 * s) ^ (l16 & 7)) << 3)];
          oacc[0][t] = __builtin_amdgcn_mfma_f32_16x16x32_bf16(pf[0][s], vf, oacc[0][t], 0, 0, 0);
          oacc[1][t] = __builtin_amdgcn_mfma_f32_16x16x32_bf16(pf[1][s], vf, oacc[1][t], 0, 0, 0);
        }
      }
      __builtin_amdgcn_s_setprio(0);
    }
  }

#pragma unroll
  for (int m = 0; m < 2; m++)
#pragma unroll
    for (int r = 0; r < 4; r++) {                    // O row q=m*16+quad*4+r, col hd=16t+l16
      float inv = 1.0f / sumacc[m][r];
      int row = b * Nc + qrow0 + wv * 32 + m * 16 + quad * 4 + r;
#pragma unroll
      for (int t = 0; t < 4; t++)
        Aout[(size_t)row * Dc + h * HDc + t * 16 + l16] = bf16cast(oacc[m][t][r] * inv);
    }
}

extern "C" void kernel_launch(void* const* d_in, const int* in_sizes, int n_in,
                              void* d_out, int out_size, void* d_ws, size_t ws_size,
                              hipStream_t stream) {
  const float* q    = (const float*)d_in[0];
  const void*  mask = d_in[1];
  const float* bias = (const float*)d_in[2];
  const float* Wq   = (const float*)d_in[3];
  const float* Wk   = (const float*)d_in[4];
  const float* Wv   = (const float*)d_in[5];
  const float* Wo   = (const float*)d_in[6];
  float* out = (float*)d_out;

  char* ws = (char*)d_ws;
  short* Wqkv = (short*)ws;  ws += (size_t)QKVNc * Dc * 2;
  short* Wob  = (short*)ws;  ws += (size_t)Dc * Dc * 2;
  short* QKV  = (short*)ws;  ws += (size_t)Mc * QKVNc * 2;
  short* aout = (short*)ws;  ws += (size_t)Mc * Dc * 2;

  cvtw_kernel<<<dim3(1024), dim3(256), 0, stream>>>(Wq, Wk, Wv, Wo, Wqkv, Wob);

  // Q cols pre-scaled by 0.125*log2e so attn can use exp2 directly.
  gemm_qkv<<<dim3(QKVNc / 192, Mc / 128), dim3(256), 0, stream>>>(
      q, Wqkv, QKV, 0.125f * L2E);
  attn_kernel<<<dim3(Bc * Hc * 16), dim3(256), 0, stream>>>(QKV, bias, mask, aout);
  gemm_out<<<dim3(Dc / 64, Mc / 128), dim3(256), 0, stream>>>(aout, Wob, out);
}